// Round 6
// baseline (228.267 us; speedup 1.0000x reference)
//
#include <hip/hip_runtime.h>
#include <hip/hip_bf16.h>
#include <math.h>

// Problem constants
#define BATCH 4
#define CIN   256
#define HH    64
#define WW    64
#define HW    4096      // HH*WW
#define COUT  64
#define KK    7
#define NTAP  49
#define NSEG  8         // j-segments in qk_stats

// exp(d/8) == exp2(d * (log2e/8)); fold scale into bf16 q
#define QSCALE 0.18033688011112042f
#define C2SCALE 0.18033688011112042f   // for fp32 path in gcalc

typedef __attribute__((ext_vector_type(8))) short bf16x8;
typedef __attribute__((ext_vector_type(4))) float f32x4;
typedef __attribute__((ext_vector_type(4))) unsigned short u16x4;

// ---------------------------------------------------------------------------
// Prep: pack [Wq;Wk;Wv] -> Wb192 bf16 [192][256] + bias192, and
//       Wout (o,c,ti,tj) -> W2b bf16 [o][t*64+c].
// ---------------------------------------------------------------------------
__global__ void prep_kernel(
    const float* __restrict__ Wq, const float* __restrict__ bq,
    const float* __restrict__ Wk, const float* __restrict__ bk,
    const float* __restrict__ Wv, const float* __restrict__ bv,
    const float* __restrict__ Wout,
    __hip_bfloat16* __restrict__ Wb192, float* __restrict__ bias192,
    __hip_bfloat16* __restrict__ W2b)
{
    const int idx = blockIdx.x * 256 + threadIdx.x;
    if (idx < 192 * 256) {
        const int row = idx >> 8, c = idx & 255;
        float wsrc;
        if (row < 64)       wsrc = Wq[row * 256 + c];
        else if (row < 128) wsrc = Wk[(row - 64) * 256 + c];
        else                wsrc = Wv[(row - 128) * 256 + c];
        Wb192[idx] = __float2bfloat16(wsrc);
        if (c == 0) {
            float bsrc;
            if (row < 64)       bsrc = bq[row];
            else if (row < 128) bsrc = bk[row - 64];
            else                bsrc = bv[row - 128];
            bias192[row] = bsrc;
        }
    } else if (idx < 192 * 256 + COUT * NTAP * COUT) {
        const int j = idx - 192 * 256;
        const int o = j / (NTAP * COUT);
        const int r = j - o * (NTAP * COUT);
        const int t = r >> 6;
        const int c = r & 63;
        W2b[j] = __float2bfloat16(Wout[((size_t)o * COUT + c) * NTAP + t]);
    }
}

// ---------------------------------------------------------------------------
// Kernel A (MFMA): QKV projection.
// grid: B*HW/16 = 1024 blocks, 256 threads = 4 waves; wave owns 3 o-tiles.
// ---------------------------------------------------------------------------
__global__ __launch_bounds__(256) void qkv_mfma(
    const float* __restrict__ x,
    const __hip_bfloat16* __restrict__ Wb192, const float* __restrict__ bias192,
    float* __restrict__ q, float* __restrict__ k, float* __restrict__ v,
    __hip_bfloat16* __restrict__ qh, __hip_bfloat16* __restrict__ kh)
{
    const int blk = blockIdx.x;          // 0..1023
    const int b   = blk >> 8;
    const int p0  = (blk & 255) * 16;    // pixel within batch
    const int tid = threadIdx.x;
    const int wv  = tid >> 6;
    const int l   = tid & 63;
    const int lg  = l >> 4, lr = l & 15;

    __shared__ __attribute__((aligned(16))) __hip_bfloat16 xsh[16 * 256];

    // stage x[c][p0..p0+15] -> bf16 LDS transposed
    {
        const int c0 = tid >> 2;         // 0..63, +64/iter
        const int p4 = tid & 3;          // float4 index within row
        const float4* xb4 = (const float4*)(x + ((size_t)b * CIN) * HW + p0);
#pragma unroll
        for (int it = 0; it < 4; ++it) {
            const int cc = c0 + it * 64;
            const float4 xv = xb4[(size_t)cc * (HW / 4) + p4];
            __hip_bfloat16* dst = &xsh[((cc >> 3) * 16) * 8 + (cc & 7)];
            dst[(p4 * 4 + 0) * 8] = __float2bfloat16(xv.x);
            dst[(p4 * 4 + 1) * 8] = __float2bfloat16(xv.y);
            dst[(p4 * 4 + 2) * 8] = __float2bfloat16(xv.z);
            dst[(p4 * 4 + 3) * 8] = __float2bfloat16(xv.w);
        }
    }
    __syncthreads();

    f32x4 acc0 = {0.f,0.f,0.f,0.f}, acc1 = {0.f,0.f,0.f,0.f}, acc2 = {0.f,0.f,0.f,0.f};
    const short* wb  = (const short*)Wb192;
    const short* xs  = (const short*)xsh;

#pragma unroll
    for (int s = 0; s < 8; ++s) {
        const bf16x8 af = *(const bf16x8*)(xs + (size_t)(((s * 4 + lg) * 16 + lr)) * 8);
        const bf16x8 b0 = *(const bf16x8*)(wb + (size_t)((wv * 3 + 0) * 16 + lr) * 256 + s * 32 + lg * 8);
        const bf16x8 b1 = *(const bf16x8*)(wb + (size_t)((wv * 3 + 1) * 16 + lr) * 256 + s * 32 + lg * 8);
        const bf16x8 b2 = *(const bf16x8*)(wb + (size_t)((wv * 3 + 2) * 16 + lr) * 256 + s * 32 + lg * 8);
        acc0 = __builtin_amdgcn_mfma_f32_16x16x32_bf16(af, b0, acc0, 0, 0, 0);
        acc1 = __builtin_amdgcn_mfma_f32_16x16x32_bf16(af, b1, acc1, 0, 0, 0);
        acc2 = __builtin_amdgcn_mfma_f32_16x16x32_bf16(af, b2, acc2, 0, 0, 0);
    }

    // epilogue: row = pixel = p0 + lg*4 + j ; col = o = (otile&3)*16 + lr
    f32x4 accs[3] = {acc0, acc1, acc2};
#pragma unroll
    for (int i = 0; i < 3; ++i) {
        const int otile = wv * 3 + i;
        const int kind  = otile >> 2;            // 0=q 1=k 2=v
        const int o     = (otile & 3) * 16 + lr;
        const float bias = bias192[otile * 16 + lr];
#pragma unroll
        for (int j = 0; j < 4; ++j) {
            const int p = p0 + lg * 4 + j;
            const size_t addr = ((size_t)b * HW + p) * (size_t)COUT + o;
            const float val = accs[i][j] + bias;
            if (kind == 0)      { q[addr] = val; qh[addr] = __float2bfloat16(val * QSCALE); }
            else if (kind == 1) { k[addr] = val; kh[addr] = __float2bfloat16(val); }
            else                { v[addr] = val; }
        }
    }
}

// ---------------------------------------------------------------------------
// Kernel B (MFMA): per-row sum of exp(qk/8), diag forced to logit 0.
// grid: 4 b x 64 panels x 8 jsegs = 2048 blocks (8 blocks/CU -> full occ).
// Per iter: TWO 16-col j-tiles with 1-deep register prefetch of the next
// pair, so L2 latency overlaps the MFMA+exp2 of the current pair.
// ---------------------------------------------------------------------------
__global__ __launch_bounds__(256) void qk_stats_mfma(
    const __hip_bfloat16* __restrict__ qh, const __hip_bfloat16* __restrict__ kh,
    float* __restrict__ s_part)
{
    const int blk   = blockIdx.x;           // 0..2047
    const int b     = blk >> 9;             // 512 blocks per batch
    const int panel = (blk >> 3) & 63;
    const int jseg  = blk & 7;
    const int tid   = threadIdx.x;
    const int w     = tid >> 6;
    const int l     = tid & 63;
    const int lg    = l >> 4;
    const int lr    = l & 15;
    const int R0    = panel * 64 + w * 16;

    const short* qb = (const short*)(qh + ((size_t)b * HW) * COUT);
    const short* kb = (const short*)(kh + ((size_t)b * HW) * COUT);

    const bf16x8 a0 = *(const bf16x8*)(qb + (size_t)(R0 + lr) * COUT + lg * 8);
    const bf16x8 a1 = *(const bf16x8*)(qb + (size_t)(R0 + lr) * COUT + 32 + lg * 8);

    float s0 = 0.f, s1 = 0.f, s2 = 0.f, s3 = 0.f;

    const int j0 = jseg * 512;
    const short* kptr = kb + (size_t)(j0 + lr) * COUT + lg * 8;

    bf16x8 p00 = *(const bf16x8*)(kptr);
    bf16x8 p01 = *(const bf16x8*)(kptr + 32);
    bf16x8 p10 = *(const bf16x8*)(kptr + 16 * COUT);
    bf16x8 p11 = *(const bf16x8*)(kptr + 16 * COUT + 32);
    kptr += 32 * COUT;

    for (int it = 0; it < 16; ++it) {
        bf16x8 n00, n01, n10, n11;
        if (it != 15) {
            n00 = *(const bf16x8*)(kptr);
            n01 = *(const bf16x8*)(kptr + 32);
            n10 = *(const bf16x8*)(kptr + 16 * COUT);
            n11 = *(const bf16x8*)(kptr + 16 * COUT + 32);
            kptr += 32 * COUT;
        }

        f32x4 dA = {0.f, 0.f, 0.f, 0.f};
        f32x4 dB = {0.f, 0.f, 0.f, 0.f};
        dA = __builtin_amdgcn_mfma_f32_16x16x32_bf16(a0, p00, dA, 0, 0, 0);
        dA = __builtin_amdgcn_mfma_f32_16x16x32_bf16(a1, p01, dA, 0, 0, 0);
        dB = __builtin_amdgcn_mfma_f32_16x16x32_bf16(a0, p10, dB, 0, 0, 0);
        dB = __builtin_amdgcn_mfma_f32_16x16x32_bf16(a1, p11, dB, 0, 0, 0);

        const int jbA = j0 + it * 32;
        const int jbB = jbA + 16;
        if (jbA == R0) {
            dA.x = (lr == lg * 4 + 0) ? 0.f : dA.x;
            dA.y = (lr == lg * 4 + 1) ? 0.f : dA.y;
            dA.z = (lr == lg * 4 + 2) ? 0.f : dA.z;
            dA.w = (lr == lg * 4 + 3) ? 0.f : dA.w;
        }
        if (jbB == R0) {
            dB.x = (lr == lg * 4 + 0) ? 0.f : dB.x;
            dB.y = (lr == lg * 4 + 1) ? 0.f : dB.y;
            dB.z = (lr == lg * 4 + 2) ? 0.f : dB.z;
            dB.w = (lr == lg * 4 + 3) ? 0.f : dB.w;
        }
        s0 += exp2f(dA.x); s1 += exp2f(dA.y); s2 += exp2f(dA.z); s3 += exp2f(dA.w);
        s0 += exp2f(dB.x); s1 += exp2f(dB.y); s2 += exp2f(dB.z); s3 += exp2f(dB.w);

        p00 = n00; p01 = n01; p10 = n10; p11 = n11;
    }

#pragma unroll
    for (int off = 1; off < 16; off <<= 1) {
        s0 += __shfl_xor(s0, off, 64);
        s1 += __shfl_xor(s1, off, 64);
        s2 += __shfl_xor(s2, off, 64);
        s3 += __shfl_xor(s3, off, 64);
    }

    if (lr == 0) {
        float4 res = {s0, s1, s2, s3};
        *(float4*)(s_part + (size_t)jseg * (BATCH * HW) + (size_t)b * HW + R0 + lg * 4) = res;
    }
}

// ---------------------------------------------------------------------------
// Kernel C1: normalized attention weights for the 49 window taps.
// grid: 4096 blocks x 256 threads (4 pixels/block, 1 tap/lane).
// ---------------------------------------------------------------------------
__global__ __launch_bounds__(256) void gcalc_kernel(
    const float* __restrict__ q, const float* __restrict__ k,
    const float* __restrict__ s_part,
    float* __restrict__ g)
{
    const int tid  = threadIdx.x;
    const int pixl = tid >> 6;
    const int t    = tid & 63;
    const int row  = blockIdx.x * 4 + pixl;      // global pixel 0..16383
    if (t >= NTAP) return;

    const int b  = row >> 12;
    const int pi = row & 4095;
    const int h  = pi >> 6, w = pi & 63;
    const int ti = t / 7, tj = t % 7;
    const int jh = min(max(h + ti - 3, 0), HH - 1);
    const int jw = min(max(w + tj - 3, 0), WW - 1);
    const int jidx = (jh << 6) | jw;

    const float4* qr = (const float4*)(q + (size_t)row * COUT);
    const float4* kr = (const float4*)(k + ((size_t)b * HW + jidx) * COUT);
    float d = 0.f;
#pragma unroll
    for (int i = 0; i < 16; ++i) {
        const float4 a = qr[i], c = kr[i];
        d += a.x * c.x + a.y * c.y + a.z * c.z + a.w * c.w;
    }
    float s = 0.f;
#pragma unroll
    for (int seg = 0; seg < NSEG; ++seg)
        s += s_part[(size_t)seg * (BATCH * HW) + row];
    const float num = (jidx == pi) ? 1.0f : exp2f(d * C2SCALE);
    g[(size_t)row * NTAP + t] = num / s;
}

// ---------------------------------------------------------------------------
// Kernel C2 (MFMA): out[b,p,o] = relu(bout[o] + sum_{t,c} gv[p][t*64+c]*W2[o][t*64+c])
// grid: 512 blocks = (b, h, half-row).  block: 256 threads = 4 waves.
// ---------------------------------------------------------------------------
__global__ __launch_bounds__(256) void out_mfma(
    const float* __restrict__ g, const float* __restrict__ v,
    const __hip_bfloat16* __restrict__ W2b, const float* __restrict__ bout,
    float* __restrict__ out)
{
    const int blk = blockIdx.x;          // 0..511
    const int b   = blk >> 7;            // 128 blocks per batch
    const int h   = (blk >> 1) & 63;
    const int w0  = (blk & 1) * 32;
    const int tid = threadIdx.x;
    const int wv  = tid >> 6;            // o-tile
    const int l   = tid & 63;
    const int lg  = l >> 4, lr = l & 15;

    __shared__ __attribute__((aligned(16))) __hip_bfloat16 gvsh[2][32][72];
    __shared__ float gsh[32][NTAP];

    const int row0 = b * HW + h * 64 + w0;     // global pixel row of local w=0
    for (int i = tid; i < 32 * NTAP; i += 256) {
        const int w = i / NTAP, t = i - w * NTAP;
        gsh[w][t] = g[(size_t)(row0 + w) * NTAP + t];
    }

    f32x4 acc0 = {0.f, 0.f, 0.f, 0.f};
    f32x4 acc1 = {0.f, 0.f, 0.f, 0.f};
    const float4* vb = (const float4*)(v + ((size_t)b * HW) * COUT);
    const short* wb  = (const short*)W2b + (size_t)(wv * 16 + lr) * (NTAP * COUT);

    const int fw = tid >> 4;             // 0..15 (w for rep0; +16 for rep1)
    const int fc4 = tid & 15;            // float4 column

    __syncthreads();

    for (int t = 0; t < NTAP; ++t) {
        const int dh = t / 7 - 3, dw = t - (t / 7) * 7 - 3;
        const int jh = min(max(h + dh, 0), HH - 1);
        __hip_bfloat16* dstbuf = &gvsh[t & 1][0][0];
#pragma unroll
        for (int rep = 0; rep < 2; ++rep) {
            const int w  = fw + rep * 16;
            const int jw = min(max(w0 + w + dw, 0), WW - 1);
            const float4 vvv = vb[(size_t)((jh << 6) + jw) * 16 + fc4];
            const float gg = gsh[w][t];
            u16x4 pk;
            pk.x = __builtin_bit_cast(unsigned short, __float2bfloat16(vvv.x * gg));
            pk.y = __builtin_bit_cast(unsigned short, __float2bfloat16(vvv.y * gg));
            pk.z = __builtin_bit_cast(unsigned short, __float2bfloat16(vvv.z * gg));
            pk.w = __builtin_bit_cast(unsigned short, __float2bfloat16(vvv.w * gg));
            *(u16x4*)(dstbuf + w * 72 + fc4 * 4) = pk;
        }
        const bf16x8 b0 = *(const bf16x8*)(wb + t * 64 + lg * 8);
        const bf16x8 b1 = *(const bf16x8*)(wb + t * 64 + 32 + lg * 8);
        __syncthreads();
        const short* gsrc = (const short*)&gvsh[t & 1][0][0];
        const bf16x8 a00 = *(const bf16x8*)(gsrc + (size_t)lr * 72 + lg * 8);
        const bf16x8 a01 = *(const bf16x8*)(gsrc + (size_t)lr * 72 + 32 + lg * 8);
        const bf16x8 a10 = *(const bf16x8*)(gsrc + (size_t)(16 + lr) * 72 + lg * 8);
        const bf16x8 a11 = *(const bf16x8*)(gsrc + (size_t)(16 + lr) * 72 + 32 + lg * 8);
        acc0 = __builtin_amdgcn_mfma_f32_16x16x32_bf16(a00, b0, acc0, 0, 0, 0);
        acc0 = __builtin_amdgcn_mfma_f32_16x16x32_bf16(a01, b1, acc0, 0, 0, 0);
        acc1 = __builtin_amdgcn_mfma_f32_16x16x32_bf16(a10, b0, acc1, 0, 0, 0);
        acc1 = __builtin_amdgcn_mfma_f32_16x16x32_bf16(a11, b1, acc1, 0, 0, 0);
    }

    const int o  = wv * 16 + lr;
    const float bo = bout[o];
    float* obase = out + ((size_t)(b * COUT + o) * HW) + h * 64 + w0 + lg * 4;
    float4 r0, r1;
    r0.x = fmaxf(acc0.x + bo, 0.f); r0.y = fmaxf(acc0.y + bo, 0.f);
    r0.z = fmaxf(acc0.z + bo, 0.f); r0.w = fmaxf(acc0.w + bo, 0.f);
    r1.x = fmaxf(acc1.x + bo, 0.f); r1.y = fmaxf(acc1.y + bo, 0.f);
    r1.z = fmaxf(acc1.z + bo, 0.f); r1.w = fmaxf(acc1.w + bo, 0.f);
    *(float4*)obase        = r0;
    *(float4*)(obase + 16) = r1;
}

// ---------------------------------------------------------------------------
extern "C" void kernel_launch(void* const* d_in, const int* in_sizes, int n_in,
                              void* d_out, int out_size, void* d_ws, size_t ws_size,
                              hipStream_t stream)
{
    const float* x    = (const float*)d_in[0];
    const float* Wq   = (const float*)d_in[1];
    const float* bq   = (const float*)d_in[2];
    const float* Wk   = (const float*)d_in[3];
    const float* bk   = (const float*)d_in[4];
    const float* Wv   = (const float*)d_in[5];
    const float* bv   = (const float*)d_in[6];
    const float* Wout = (const float*)d_in[7];
    const float* bout = (const float*)d_in[8];
    float* out = (float*)d_out;

    // workspace layout (float units)
    float* ws     = (float*)d_ws;
    float* q      = ws;                                  // 1,048,576
    float* k      = q + (size_t)BATCH * HW * COUT;
    float* v      = k + (size_t)BATCH * HW * COUT;
    float* s_part = v + (size_t)BATCH * HW * COUT;       // NSEG * B*HW
    float* g      = s_part + (size_t)NSEG * BATCH * HW;  // 802,816
    float* bias192 = g + (size_t)BATCH * HW * NTAP;      // 192
    __hip_bfloat16* qh    = (__hip_bfloat16*)(bias192 + 256);
    __hip_bfloat16* kh    = qh + (size_t)BATCH * HW * COUT;
    __hip_bfloat16* W2b   = kh + (size_t)BATCH * HW * COUT;   // 200,704 bf16
    __hip_bfloat16* Wb192 = W2b + (size_t)COUT * NTAP * COUT; // 49,152 bf16

    prep_kernel<<<(192 * 256 + COUT * NTAP * COUT + 255) / 256, 256, 0, stream>>>(
        Wq, bq, Wk, bk, Wv, bv, Wout, Wb192, bias192, W2b);
    qkv_mfma<<<BATCH * (HW / 16), 256, 0, stream>>>(x, Wb192, bias192, q, k, v, qh, kh);
    qk_stats_mfma<<<BATCH * 64 * NSEG, 256, 0, stream>>>(qh, kh, s_part);
    gcalc_kernel<<<BATCH * HW / 4, 256, 0, stream>>>(q, k, s_part, g);
    out_mfma<<<512, 256, 0, stream>>>(g, v, W2b, bout, out);
}

// Round 7
// 207.527 us; speedup vs baseline: 1.0999x; 1.0999x over previous
//
#include <hip/hip_runtime.h>
#include <hip/hip_bf16.h>
#include <math.h>

// Problem constants
#define BATCH 4
#define CIN   256
#define HH    64
#define WW    64
#define HW    4096      // HH*WW
#define COUT  64
#define KK    7
#define NTAP  49
#define NSEG  16        // j-segments in qk_stats (256 cols each)

// exp(d/8) == exp2(d * (log2e/8)); fold scale into bf16 q
#define QSCALE 0.18033688011112042f
#define C2SCALE 0.18033688011112042f   // for fp32 path in gcalc

typedef __attribute__((ext_vector_type(8))) short bf16x8;
typedef __attribute__((ext_vector_type(4))) float f32x4;
typedef __attribute__((ext_vector_type(4))) unsigned short u16x4;

// ---------------------------------------------------------------------------
// Prep: pack [Wq;Wk;Wv] -> Wb192 bf16 [192][256] + bias192, and
//       Wout (o,c,ti,tj) -> W2b bf16 [o][t*64+c].
// ---------------------------------------------------------------------------
__global__ void prep_kernel(
    const float* __restrict__ Wq, const float* __restrict__ bq,
    const float* __restrict__ Wk, const float* __restrict__ bk,
    const float* __restrict__ Wv, const float* __restrict__ bv,
    const float* __restrict__ Wout,
    __hip_bfloat16* __restrict__ Wb192, float* __restrict__ bias192,
    __hip_bfloat16* __restrict__ W2b)
{
    const int idx = blockIdx.x * 256 + threadIdx.x;
    if (idx < 192 * 256) {
        const int row = idx >> 8, c = idx & 255;
        float wsrc;
        if (row < 64)       wsrc = Wq[row * 256 + c];
        else if (row < 128) wsrc = Wk[(row - 64) * 256 + c];
        else                wsrc = Wv[(row - 128) * 256 + c];
        Wb192[idx] = __float2bfloat16(wsrc);
        if (c == 0) {
            float bsrc;
            if (row < 64)       bsrc = bq[row];
            else if (row < 128) bsrc = bk[row - 64];
            else                bsrc = bv[row - 128];
            bias192[row] = bsrc;
        }
    } else if (idx < 192 * 256 + COUT * NTAP * COUT) {
        const int j = idx - 192 * 256;
        const int o = j / (NTAP * COUT);
        const int r = j - o * (NTAP * COUT);
        const int t = r >> 6;
        const int c = r & 63;
        W2b[j] = __float2bfloat16(Wout[((size_t)o * COUT + c) * NTAP + t]);
    }
}

// ---------------------------------------------------------------------------
// Kernel A (MFMA): QKV projection.
// grid: B*HW/16 = 1024 blocks, 256 threads = 4 waves; wave owns 3 o-tiles.
// ---------------------------------------------------------------------------
__global__ __launch_bounds__(256) void qkv_mfma(
    const float* __restrict__ x,
    const __hip_bfloat16* __restrict__ Wb192, const float* __restrict__ bias192,
    float* __restrict__ q, float* __restrict__ k, float* __restrict__ v,
    __hip_bfloat16* __restrict__ qh, __hip_bfloat16* __restrict__ kh)
{
    const int blk = blockIdx.x;          // 0..1023
    const int b   = blk >> 8;
    const int p0  = (blk & 255) * 16;    // pixel within batch
    const int tid = threadIdx.x;
    const int wv  = tid >> 6;
    const int l   = tid & 63;
    const int lg  = l >> 4, lr = l & 15;

    __shared__ __attribute__((aligned(16))) __hip_bfloat16 xsh[16 * 256];

    // stage x[c][p0..p0+15] -> bf16 LDS transposed
    {
        const int c0 = tid >> 2;         // 0..63, +64/iter
        const int p4 = tid & 3;          // float4 index within row
        const float4* xb4 = (const float4*)(x + ((size_t)b * CIN) * HW + p0);
#pragma unroll
        for (int it = 0; it < 4; ++it) {
            const int cc = c0 + it * 64;
            const float4 xv = xb4[(size_t)cc * (HW / 4) + p4];
            __hip_bfloat16* dst = &xsh[((cc >> 3) * 16) * 8 + (cc & 7)];
            dst[(p4 * 4 + 0) * 8] = __float2bfloat16(xv.x);
            dst[(p4 * 4 + 1) * 8] = __float2bfloat16(xv.y);
            dst[(p4 * 4 + 2) * 8] = __float2bfloat16(xv.z);
            dst[(p4 * 4 + 3) * 8] = __float2bfloat16(xv.w);
        }
    }
    __syncthreads();

    f32x4 acc0 = {0.f,0.f,0.f,0.f}, acc1 = {0.f,0.f,0.f,0.f}, acc2 = {0.f,0.f,0.f,0.f};
    const short* wb  = (const short*)Wb192;
    const short* xs  = (const short*)xsh;

#pragma unroll
    for (int s = 0; s < 8; ++s) {
        const bf16x8 af = *(const bf16x8*)(xs + (size_t)(((s * 4 + lg) * 16 + lr)) * 8);
        const bf16x8 b0 = *(const bf16x8*)(wb + (size_t)((wv * 3 + 0) * 16 + lr) * 256 + s * 32 + lg * 8);
        const bf16x8 b1 = *(const bf16x8*)(wb + (size_t)((wv * 3 + 1) * 16 + lr) * 256 + s * 32 + lg * 8);
        const bf16x8 b2 = *(const bf16x8*)(wb + (size_t)((wv * 3 + 2) * 16 + lr) * 256 + s * 32 + lg * 8);
        acc0 = __builtin_amdgcn_mfma_f32_16x16x32_bf16(af, b0, acc0, 0, 0, 0);
        acc1 = __builtin_amdgcn_mfma_f32_16x16x32_bf16(af, b1, acc1, 0, 0, 0);
        acc2 = __builtin_amdgcn_mfma_f32_16x16x32_bf16(af, b2, acc2, 0, 0, 0);
    }

    // epilogue: row = pixel = p0 + lg*4 + j ; col = o = (otile&3)*16 + lr
    f32x4 accs[3] = {acc0, acc1, acc2};
#pragma unroll
    for (int i = 0; i < 3; ++i) {
        const int otile = wv * 3 + i;
        const int kind  = otile >> 2;            // 0=q 1=k 2=v
        const int o     = (otile & 3) * 16 + lr;
        const float bias = bias192[otile * 16 + lr];
#pragma unroll
        for (int j = 0; j < 4; ++j) {
            const int p = p0 + lg * 4 + j;
            const size_t addr = ((size_t)b * HW + p) * (size_t)COUT + o;
            const float val = accs[i][j] + bias;
            if (kind == 0)      { q[addr] = val; qh[addr] = __float2bfloat16(val * QSCALE); }
            else if (kind == 1) { k[addr] = val; kh[addr] = __float2bfloat16(val); }
            else                { v[addr] = val; }
        }
    }
}

// ---------------------------------------------------------------------------
// Kernel B (MFMA): per-row sum of exp(qk/8), diag forced to logit 0.
// grid: 4 b x 16 panels(256 rows) x 16 jsegs(256 cols) = 1024 blocks.
// Wave owns 64 Q-rows (4 row-tiles in registers) -> one K-pair load (2KB)
// feeds 8 MFMA, cutting K re-read traffic 4x vs the 16-row version.
// 1-deep register prefetch of the next K pair overlaps L2 latency.
// ---------------------------------------------------------------------------
__global__ __launch_bounds__(256) void qk_stats_mfma(
    const __hip_bfloat16* __restrict__ qh, const __hip_bfloat16* __restrict__ kh,
    float* __restrict__ s_part)
{
    const int blk   = blockIdx.x;           // 0..1023
    const int b     = blk >> 8;             // 256 blocks per batch
    const int panel = (blk >> 4) & 15;      // 256-row panel
    const int jseg  = blk & 15;             // 256-col segment
    const int tid   = threadIdx.x;
    const int w     = tid >> 6;
    const int l     = tid & 63;
    const int lg    = l >> 4;
    const int lr    = l & 15;
    const int R0    = panel * 256 + w * 64; // wave's first Q row

    const short* qb = (const short*)(qh + ((size_t)b * HW) * COUT);
    const short* kb = (const short*)(kh + ((size_t)b * HW) * COUT);

    // A fragments: 4 row-tiles x 2 k-slices
    bf16x8 a[4][2];
#pragma unroll
    for (int rt = 0; rt < 4; ++rt) {
        a[rt][0] = *(const bf16x8*)(qb + (size_t)(R0 + rt * 16 + lr) * COUT + lg * 8);
        a[rt][1] = *(const bf16x8*)(qb + (size_t)(R0 + rt * 16 + lr) * COUT + 32 + lg * 8);
    }

    float s[4][4];
#pragma unroll
    for (int rt = 0; rt < 4; ++rt)
#pragma unroll
        for (int i = 0; i < 4; ++i) s[rt][i] = 0.f;

    const int j0 = jseg * 256;
    const short* kptr = kb + (size_t)(j0 + lr) * COUT + lg * 8;

    bf16x8 p0 = *(const bf16x8*)(kptr);
    bf16x8 p1 = *(const bf16x8*)(kptr + 32);
    kptr += 16 * COUT;

    for (int it = 0; it < 16; ++it) {
        bf16x8 n0, n1;
        if (it != 15) {
            n0 = *(const bf16x8*)(kptr);
            n1 = *(const bf16x8*)(kptr + 32);
            kptr += 16 * COUT;
        }
        const int jb = j0 + it * 16;
#pragma unroll
        for (int rt = 0; rt < 4; ++rt) {
            f32x4 d = {0.f, 0.f, 0.f, 0.f};
            d = __builtin_amdgcn_mfma_f32_16x16x32_bf16(a[rt][0], p0, d, 0, 0, 0);
            d = __builtin_amdgcn_mfma_f32_16x16x32_bf16(a[rt][1], p1, d, 0, 0, 0);
            if (jb == R0 + rt * 16) {
                d.x = (lr == lg * 4 + 0) ? 0.f : d.x;
                d.y = (lr == lg * 4 + 1) ? 0.f : d.y;
                d.z = (lr == lg * 4 + 2) ? 0.f : d.z;
                d.w = (lr == lg * 4 + 3) ? 0.f : d.w;
            }
            s[rt][0] += exp2f(d.x);
            s[rt][1] += exp2f(d.y);
            s[rt][2] += exp2f(d.z);
            s[rt][3] += exp2f(d.w);
        }
        p0 = n0; p1 = n1;
    }

    // reduce across the 16 lanes sharing a row-group, per row-tile
#pragma unroll
    for (int rt = 0; rt < 4; ++rt) {
#pragma unroll
        for (int off = 1; off < 16; off <<= 1) {
            s[rt][0] += __shfl_xor(s[rt][0], off, 64);
            s[rt][1] += __shfl_xor(s[rt][1], off, 64);
            s[rt][2] += __shfl_xor(s[rt][2], off, 64);
            s[rt][3] += __shfl_xor(s[rt][3], off, 64);
        }
        if (lr == 0) {
            float4 res = {s[rt][0], s[rt][1], s[rt][2], s[rt][3]};
            *(float4*)(s_part + (size_t)jseg * (BATCH * HW) + (size_t)b * HW +
                       R0 + rt * 16 + lg * 4) = res;
        }
    }
}

// ---------------------------------------------------------------------------
// Kernel C1: normalized attention weights for the 49 window taps.
// grid: 4096 blocks x 256 threads (4 pixels/block, 1 tap/lane).
// ---------------------------------------------------------------------------
__global__ __launch_bounds__(256) void gcalc_kernel(
    const float* __restrict__ q, const float* __restrict__ k,
    const float* __restrict__ s_part,
    float* __restrict__ g)
{
    const int tid  = threadIdx.x;
    const int pixl = tid >> 6;
    const int t    = tid & 63;
    const int row  = blockIdx.x * 4 + pixl;      // global pixel 0..16383
    if (t >= NTAP) return;

    const int b  = row >> 12;
    const int pi = row & 4095;
    const int h  = pi >> 6, w = pi & 63;
    const int ti = t / 7, tj = t % 7;
    const int jh = min(max(h + ti - 3, 0), HH - 1);
    const int jw = min(max(w + tj - 3, 0), WW - 1);
    const int jidx = (jh << 6) | jw;

    const float4* qr = (const float4*)(q + (size_t)row * COUT);
    const float4* kr = (const float4*)(k + ((size_t)b * HW + jidx) * COUT);
    float d = 0.f;
#pragma unroll
    for (int i = 0; i < 16; ++i) {
        const float4 a = qr[i], c = kr[i];
        d += a.x * c.x + a.y * c.y + a.z * c.z + a.w * c.w;
    }
    float s = 0.f;
#pragma unroll
    for (int seg = 0; seg < NSEG; ++seg)
        s += s_part[(size_t)seg * (BATCH * HW) + row];
    const float num = (jidx == pi) ? 1.0f : exp2f(d * C2SCALE);
    g[(size_t)row * NTAP + t] = num / s;
}

// ---------------------------------------------------------------------------
// Kernel C2 (MFMA): out[b,p,o] = relu(bout[o] + sum_{t,c} gv[p][t*64+c]*W2[o][t*64+c])
// grid: 512 blocks = (b, h, half-row).  block: 256 threads = 4 waves.
// ---------------------------------------------------------------------------
__global__ __launch_bounds__(256) void out_mfma(
    const float* __restrict__ g, const float* __restrict__ v,
    const __hip_bfloat16* __restrict__ W2b, const float* __restrict__ bout,
    float* __restrict__ out)
{
    const int blk = blockIdx.x;          // 0..511
    const int b   = blk >> 7;            // 128 blocks per batch
    const int h   = (blk >> 1) & 63;
    const int w0  = (blk & 1) * 32;
    const int tid = threadIdx.x;
    const int wv  = tid >> 6;            // o-tile
    const int l   = tid & 63;
    const int lg  = l >> 4, lr = l & 15;

    __shared__ __attribute__((aligned(16))) __hip_bfloat16 gvsh[2][32][72];
    __shared__ float gsh[32][NTAP];

    const int row0 = b * HW + h * 64 + w0;     // global pixel row of local w=0
    for (int i = tid; i < 32 * NTAP; i += 256) {
        const int w = i / NTAP, t = i - w * NTAP;
        gsh[w][t] = g[(size_t)(row0 + w) * NTAP + t];
    }

    f32x4 acc0 = {0.f, 0.f, 0.f, 0.f};
    f32x4 acc1 = {0.f, 0.f, 0.f, 0.f};
    const float4* vb = (const float4*)(v + ((size_t)b * HW) * COUT);
    const short* wb  = (const short*)W2b + (size_t)(wv * 16 + lr) * (NTAP * COUT);

    const int fw = tid >> 4;             // 0..15 (w for rep0; +16 for rep1)
    const int fc4 = tid & 15;            // float4 column

    __syncthreads();

    for (int t = 0; t < NTAP; ++t) {
        const int dh = t / 7 - 3, dw = t - (t / 7) * 7 - 3;
        const int jh = min(max(h + dh, 0), HH - 1);
        __hip_bfloat16* dstbuf = &gvsh[t & 1][0][0];
#pragma unroll
        for (int rep = 0; rep < 2; ++rep) {
            const int w  = fw + rep * 16;
            const int jw = min(max(w0 + w + dw, 0), WW - 1);
            const float4 vvv = vb[(size_t)((jh << 6) + jw) * 16 + fc4];
            const float gg = gsh[w][t];
            u16x4 pk;
            pk.x = __builtin_bit_cast(unsigned short, __float2bfloat16(vvv.x * gg));
            pk.y = __builtin_bit_cast(unsigned short, __float2bfloat16(vvv.y * gg));
            pk.z = __builtin_bit_cast(unsigned short, __float2bfloat16(vvv.z * gg));
            pk.w = __builtin_bit_cast(unsigned short, __float2bfloat16(vvv.w * gg));
            *(u16x4*)(dstbuf + w * 72 + fc4 * 4) = pk;
        }
        const bf16x8 b0 = *(const bf16x8*)(wb + t * 64 + lg * 8);
        const bf16x8 b1 = *(const bf16x8*)(wb + t * 64 + 32 + lg * 8);
        __syncthreads();
        const short* gsrc = (const short*)&gvsh[t & 1][0][0];
        const bf16x8 a00 = *(const bf16x8*)(gsrc + (size_t)lr * 72 + lg * 8);
        const bf16x8 a01 = *(const bf16x8*)(gsrc + (size_t)lr * 72 + 32 + lg * 8);
        const bf16x8 a10 = *(const bf16x8*)(gsrc + (size_t)(16 + lr) * 72 + lg * 8);
        const bf16x8 a11 = *(const bf16x8*)(gsrc + (size_t)(16 + lr) * 72 + 32 + lg * 8);
        acc0 = __builtin_amdgcn_mfma_f32_16x16x32_bf16(a00, b0, acc0, 0, 0, 0);
        acc0 = __builtin_amdgcn_mfma_f32_16x16x32_bf16(a01, b1, acc0, 0, 0, 0);
        acc1 = __builtin_amdgcn_mfma_f32_16x16x32_bf16(a10, b0, acc1, 0, 0, 0);
        acc1 = __builtin_amdgcn_mfma_f32_16x16x32_bf16(a11, b1, acc1, 0, 0, 0);
    }

    const int o  = wv * 16 + lr;
    const float bo = bout[o];
    float* obase = out + ((size_t)(b * COUT + o) * HW) + h * 64 + w0 + lg * 4;
    float4 r0, r1;
    r0.x = fmaxf(acc0.x + bo, 0.f); r0.y = fmaxf(acc0.y + bo, 0.f);
    r0.z = fmaxf(acc0.z + bo, 0.f); r0.w = fmaxf(acc0.w + bo, 0.f);
    r1.x = fmaxf(acc1.x + bo, 0.f); r1.y = fmaxf(acc1.y + bo, 0.f);
    r1.z = fmaxf(acc1.z + bo, 0.f); r1.w = fmaxf(acc1.w + bo, 0.f);
    *(float4*)obase        = r0;
    *(float4*)(obase + 16) = r1;
}

// ---------------------------------------------------------------------------
extern "C" void kernel_launch(void* const* d_in, const int* in_sizes, int n_in,
                              void* d_out, int out_size, void* d_ws, size_t ws_size,
                              hipStream_t stream)
{
    const float* x    = (const float*)d_in[0];
    const float* Wq   = (const float*)d_in[1];
    const float* bq   = (const float*)d_in[2];
    const float* Wk   = (const float*)d_in[3];
    const float* bk   = (const float*)d_in[4];
    const float* Wv   = (const float*)d_in[5];
    const float* bv   = (const float*)d_in[6];
    const float* Wout = (const float*)d_in[7];
    const float* bout = (const float*)d_in[8];
    float* out = (float*)d_out;

    // workspace layout (float units)
    float* ws     = (float*)d_ws;
    float* q      = ws;                                  // 1,048,576
    float* k      = q + (size_t)BATCH * HW * COUT;
    float* v      = k + (size_t)BATCH * HW * COUT;
    float* s_part = v + (size_t)BATCH * HW * COUT;       // NSEG * B*HW
    float* g      = s_part + (size_t)NSEG * BATCH * HW;  // 802,816
    float* bias192 = g + (size_t)BATCH * HW * NTAP;      // 192
    __hip_bfloat16* qh    = (__hip_bfloat16*)(bias192 + 256);
    __hip_bfloat16* kh    = qh + (size_t)BATCH * HW * COUT;
    __hip_bfloat16* W2b   = kh + (size_t)BATCH * HW * COUT;   // 200,704 bf16
    __hip_bfloat16* Wb192 = W2b + (size_t)COUT * NTAP * COUT; // 49,152 bf16

    prep_kernel<<<(192 * 256 + COUT * NTAP * COUT + 255) / 256, 256, 0, stream>>>(
        Wq, bq, Wk, bk, Wv, bv, Wout, Wb192, bias192, W2b);
    qkv_mfma<<<BATCH * (HW / 16), 256, 0, stream>>>(x, Wb192, bias192, q, k, v, qh, kh);
    qk_stats_mfma<<<BATCH * 16 * NSEG, 256, 0, stream>>>(qh, kh, s_part);
    gcalc_kernel<<<BATCH * HW / 4, 256, 0, stream>>>(q, k, s_part, g);
    out_mfma<<<512, 256, 0, stream>>>(g, v, W2b, bout, out);
}

// Round 8
// 183.502 us; speedup vs baseline: 1.2439x; 1.1309x over previous
//
#include <hip/hip_runtime.h>
#include <hip/hip_bf16.h>
#include <math.h>

// Problem constants
#define BATCH 4
#define CIN   256
#define HH    64
#define WW    64
#define HW    4096      // HH*WW
#define COUT  64
#define KK    7
#define NTAP  49
#define NSEG  16        // j-segments in qk_stats (256 cols each)

// exp(d/8) == exp2(d * (log2e/8)); fold scale into bf16 q
#define QSCALE 0.18033688011112042f

typedef __attribute__((ext_vector_type(8))) short bf16x8;
typedef __attribute__((ext_vector_type(4))) float f32x4;
typedef __attribute__((ext_vector_type(4))) unsigned short u16x4;

// ---------------------------------------------------------------------------
// Prep: pack [Wq;Wk;Wv] -> Wb192 bf16 [192][256] + bias192, and
//       Wout (o,c,ti,tj) -> W2b bf16 [o][t*64+c].
// ---------------------------------------------------------------------------
__global__ void prep_kernel(
    const float* __restrict__ Wq, const float* __restrict__ bq,
    const float* __restrict__ Wk, const float* __restrict__ bk,
    const float* __restrict__ Wv, const float* __restrict__ bv,
    const float* __restrict__ Wout,
    __hip_bfloat16* __restrict__ Wb192, float* __restrict__ bias192,
    __hip_bfloat16* __restrict__ W2b)
{
    const int idx = blockIdx.x * 256 + threadIdx.x;
    if (idx < 192 * 256) {
        const int row = idx >> 8, c = idx & 255;
        float wsrc;
        if (row < 64)       wsrc = Wq[row * 256 + c];
        else if (row < 128) wsrc = Wk[(row - 64) * 256 + c];
        else                wsrc = Wv[(row - 128) * 256 + c];
        Wb192[idx] = __float2bfloat16(wsrc);
        if (c == 0) {
            float bsrc;
            if (row < 64)       bsrc = bq[row];
            else if (row < 128) bsrc = bk[row - 64];
            else                bsrc = bv[row - 128];
            bias192[row] = bsrc;
        }
    } else if (idx < 192 * 256 + COUT * NTAP * COUT) {
        const int j = idx - 192 * 256;
        const int o = j / (NTAP * COUT);
        const int r = j - o * (NTAP * COUT);
        const int t = r >> 6;
        const int c = r & 63;
        W2b[j] = __float2bfloat16(Wout[((size_t)o * COUT + c) * NTAP + t]);
    }
}

// ---------------------------------------------------------------------------
// Kernel A (MFMA): QKV projection.  Writes v fp32 + qh (pre-scaled bf16) + kh.
// grid: B*HW/16 = 1024 blocks, 256 threads = 4 waves; wave owns 3 o-tiles.
// ---------------------------------------------------------------------------
__global__ __launch_bounds__(256) void qkv_mfma(
    const float* __restrict__ x,
    const __hip_bfloat16* __restrict__ Wb192, const float* __restrict__ bias192,
    float* __restrict__ v,
    __hip_bfloat16* __restrict__ qh, __hip_bfloat16* __restrict__ kh)
{
    const int blk = blockIdx.x;          // 0..1023
    const int b   = blk >> 8;
    const int p0  = (blk & 255) * 16;    // pixel within batch
    const int tid = threadIdx.x;
    const int wv  = tid >> 6;
    const int l   = tid & 63;
    const int lg  = l >> 4, lr = l & 15;

    __shared__ __attribute__((aligned(16))) __hip_bfloat16 xsh[16 * 256];

    // stage x[c][p0..p0+15] -> bf16 LDS transposed
    {
        const int c0 = tid >> 2;         // 0..63, +64/iter
        const int p4 = tid & 3;          // float4 index within row
        const float4* xb4 = (const float4*)(x + ((size_t)b * CIN) * HW + p0);
#pragma unroll
        for (int it = 0; it < 4; ++it) {
            const int cc = c0 + it * 64;
            const float4 xv = xb4[(size_t)cc * (HW / 4) + p4];
            __hip_bfloat16* dst = &xsh[((cc >> 3) * 16) * 8 + (cc & 7)];
            dst[(p4 * 4 + 0) * 8] = __float2bfloat16(xv.x);
            dst[(p4 * 4 + 1) * 8] = __float2bfloat16(xv.y);
            dst[(p4 * 4 + 2) * 8] = __float2bfloat16(xv.z);
            dst[(p4 * 4 + 3) * 8] = __float2bfloat16(xv.w);
        }
    }
    __syncthreads();

    f32x4 acc0 = {0.f,0.f,0.f,0.f}, acc1 = {0.f,0.f,0.f,0.f}, acc2 = {0.f,0.f,0.f,0.f};
    const short* wb  = (const short*)Wb192;
    const short* xs  = (const short*)xsh;

#pragma unroll
    for (int s = 0; s < 8; ++s) {
        const bf16x8 af = *(const bf16x8*)(xs + (size_t)(((s * 4 + lg) * 16 + lr)) * 8);
        const bf16x8 b0 = *(const bf16x8*)(wb + (size_t)((wv * 3 + 0) * 16 + lr) * 256 + s * 32 + lg * 8);
        const bf16x8 b1 = *(const bf16x8*)(wb + (size_t)((wv * 3 + 1) * 16 + lr) * 256 + s * 32 + lg * 8);
        const bf16x8 b2 = *(const bf16x8*)(wb + (size_t)((wv * 3 + 2) * 16 + lr) * 256 + s * 32 + lg * 8);
        acc0 = __builtin_amdgcn_mfma_f32_16x16x32_bf16(af, b0, acc0, 0, 0, 0);
        acc1 = __builtin_amdgcn_mfma_f32_16x16x32_bf16(af, b1, acc1, 0, 0, 0);
        acc2 = __builtin_amdgcn_mfma_f32_16x16x32_bf16(af, b2, acc2, 0, 0, 0);
    }

    // epilogue: row = pixel = p0 + lg*4 + j ; col = o = (otile&3)*16 + lr
    f32x4 accs[3] = {acc0, acc1, acc2};
#pragma unroll
    for (int i = 0; i < 3; ++i) {
        const int otile = wv * 3 + i;
        const int kind  = otile >> 2;            // 0=q 1=k 2=v
        const int o     = (otile & 3) * 16 + lr;
        const float bias = bias192[otile * 16 + lr];
#pragma unroll
        for (int j = 0; j < 4; ++j) {
            const int p = p0 + lg * 4 + j;
            const size_t addr = ((size_t)b * HW + p) * (size_t)COUT + o;
            const float val = accs[i][j] + bias;
            if (kind == 0)      { qh[addr] = __float2bfloat16(val * QSCALE); }
            else if (kind == 1) { kh[addr] = __float2bfloat16(val); }
            else                { v[addr] = val; }
        }
    }
}

// ---------------------------------------------------------------------------
// Kernel B (MFMA): per-row sum of exp(qk/8), diag forced to logit 0.
// grid: 4 b x 16 panels(256 rows) x 16 jsegs(256 cols) = 1024 blocks.
// Wave owns 64 Q-rows (4 row-tiles in registers); 1-deep K prefetch.
// ---------------------------------------------------------------------------
__global__ __launch_bounds__(256) void qk_stats_mfma(
    const __hip_bfloat16* __restrict__ qh, const __hip_bfloat16* __restrict__ kh,
    float* __restrict__ s_part)
{
    const int blk   = blockIdx.x;           // 0..1023
    const int b     = blk >> 8;             // 256 blocks per batch
    const int panel = (blk >> 4) & 15;      // 256-row panel
    const int jseg  = blk & 15;             // 256-col segment
    const int tid   = threadIdx.x;
    const int w     = tid >> 6;
    const int l     = tid & 63;
    const int lg    = l >> 4;
    const int lr    = l & 15;
    const int R0    = panel * 256 + w * 64; // wave's first Q row

    const short* qb = (const short*)(qh + ((size_t)b * HW) * COUT);
    const short* kb = (const short*)(kh + ((size_t)b * HW) * COUT);

    // A fragments: 4 row-tiles x 2 k-slices
    bf16x8 a[4][2];
#pragma unroll
    for (int rt = 0; rt < 4; ++rt) {
        a[rt][0] = *(const bf16x8*)(qb + (size_t)(R0 + rt * 16 + lr) * COUT + lg * 8);
        a[rt][1] = *(const bf16x8*)(qb + (size_t)(R0 + rt * 16 + lr) * COUT + 32 + lg * 8);
    }

    float s[4][4];
#pragma unroll
    for (int rt = 0; rt < 4; ++rt)
#pragma unroll
        for (int i = 0; i < 4; ++i) s[rt][i] = 0.f;

    const int j0 = jseg * 256;
    const short* kptr = kb + (size_t)(j0 + lr) * COUT + lg * 8;

    bf16x8 p0 = *(const bf16x8*)(kptr);
    bf16x8 p1 = *(const bf16x8*)(kptr + 32);
    kptr += 16 * COUT;

    for (int it = 0; it < 16; ++it) {
        bf16x8 n0, n1;
        if (it != 15) {
            n0 = *(const bf16x8*)(kptr);
            n1 = *(const bf16x8*)(kptr + 32);
            kptr += 16 * COUT;
        }
        const int jb = j0 + it * 16;
#pragma unroll
        for (int rt = 0; rt < 4; ++rt) {
            f32x4 d = {0.f, 0.f, 0.f, 0.f};
            d = __builtin_amdgcn_mfma_f32_16x16x32_bf16(a[rt][0], p0, d, 0, 0, 0);
            d = __builtin_amdgcn_mfma_f32_16x16x32_bf16(a[rt][1], p1, d, 0, 0, 0);
            if (jb == R0 + rt * 16) {
                d.x = (lr == lg * 4 + 0) ? 0.f : d.x;
                d.y = (lr == lg * 4 + 1) ? 0.f : d.y;
                d.z = (lr == lg * 4 + 2) ? 0.f : d.z;
                d.w = (lr == lg * 4 + 3) ? 0.f : d.w;
            }
            s[rt][0] += exp2f(d.x);
            s[rt][1] += exp2f(d.y);
            s[rt][2] += exp2f(d.z);
            s[rt][3] += exp2f(d.w);
        }
        p0 = n0; p1 = n1;
    }

    // reduce across the 16 lanes sharing a row-group, per row-tile
#pragma unroll
    for (int rt = 0; rt < 4; ++rt) {
#pragma unroll
        for (int off = 1; off < 16; off <<= 1) {
            s[rt][0] += __shfl_xor(s[rt][0], off, 64);
            s[rt][1] += __shfl_xor(s[rt][1], off, 64);
            s[rt][2] += __shfl_xor(s[rt][2], off, 64);
            s[rt][3] += __shfl_xor(s[rt][3], off, 64);
        }
        if (lr == 0) {
            float4 res = {s[rt][0], s[rt][1], s[rt][2], s[rt][3]};
            *(float4*)(s_part + (size_t)jseg * (BATCH * HW) + (size_t)b * HW +
                       R0 + rt * 16 + lg * 4) = res;
        }
    }
}

// ---------------------------------------------------------------------------
// Kernel C1 (MFMA): banded window attention weights.
// For block (b,h,dh): D[w][c] = qh[h*64+w] . kh[jh*64+c]  (64x64x64 GEMM),
// staged in LDS, then the 7-wide band (dw) extracted: g = exp2(D)/s.
// grid: B*HH*7 = 1792 blocks (7/CU), 256 threads = 4 waves (16 rows each).
// ---------------------------------------------------------------------------
__global__ __launch_bounds__(256) void gcalc_mfma(
    const __hip_bfloat16* __restrict__ qh, const __hip_bfloat16* __restrict__ kh,
    const float* __restrict__ s_part, float* __restrict__ g)
{
    const int blk = blockIdx.x;            // ((b*64+h)*7 + dh)
    const int dh  = blk % 7;
    const int bh  = blk / 7;
    const int h   = bh & 63;
    const int b   = bh >> 6;
    const int tid = threadIdx.x;
    const int wv  = tid >> 6;
    const int l   = tid & 63;
    const int lg  = l >> 4, lr = l & 15;

    const int jh = min(max(h + dh - 3, 0), HH - 1);

    __shared__ float Dsh[64][65];
    __shared__ float rsh[64];

    // reciprocal row sums (denominator)
    if (tid < 64) {
        float s = 0.f;
        const size_t base = (size_t)b * HW + h * 64 + tid;
#pragma unroll
        for (int seg = 0; seg < NSEG; ++seg)
            s += s_part[(size_t)seg * (BATCH * HW) + base];
        rsh[tid] = 1.0f / s;
    }

    const short* qb = (const short*)(qh + ((size_t)b * HW + h * 64) * COUT);
    const short* kb = (const short*)(kh + ((size_t)b * HW + jh * 64) * COUT);

    const bf16x8 a0 = *(const bf16x8*)(qb + (size_t)(wv * 16 + lr) * COUT + lg * 8);
    const bf16x8 a1 = *(const bf16x8*)(qb + (size_t)(wv * 16 + lr) * COUT + 32 + lg * 8);

#pragma unroll
    for (int ct = 0; ct < 4; ++ct) {
        const bf16x8 b0 = *(const bf16x8*)(kb + (size_t)(ct * 16 + lr) * COUT + lg * 8);
        const bf16x8 b1 = *(const bf16x8*)(kb + (size_t)(ct * 16 + lr) * COUT + 32 + lg * 8);
        f32x4 d = {0.f, 0.f, 0.f, 0.f};
        d = __builtin_amdgcn_mfma_f32_16x16x32_bf16(a0, b0, d, 0, 0, 0);
        d = __builtin_amdgcn_mfma_f32_16x16x32_bf16(a1, b1, d, 0, 0, 0);
        const int row = wv * 16 + lg * 4;
        const int col = ct * 16 + lr;
        Dsh[row + 0][col] = d.x;
        Dsh[row + 1][col] = d.y;
        Dsh[row + 2][col] = d.z;
        Dsh[row + 3][col] = d.w;
    }
    __syncthreads();

    // band extraction: 64 w x 7 tj entries
    for (int e = tid; e < 64 * 7; e += 256) {
        const int w  = e / 7;
        const int tj = e - w * 7;
        const int jw = min(max(w + tj - 3, 0), WW - 1);
        const float num = (jh == h && jw == w) ? 1.0f : exp2f(Dsh[w][jw]);
        g[((size_t)b * HW + h * 64 + w) * NTAP + dh * 7 + tj] = num * rsh[w];
    }
}

// ---------------------------------------------------------------------------
// Kernel C2 (MFMA): out[b,p,o] = relu(bout[o] + sum_{t,c} gv[p][t*64+c]*W2[o][t*64+c])
// grid: 512 blocks = (b, h, half-row).  block: 256 threads = 4 waves.
// ---------------------------------------------------------------------------
__global__ __launch_bounds__(256) void out_mfma(
    const float* __restrict__ g, const float* __restrict__ v,
    const __hip_bfloat16* __restrict__ W2b, const float* __restrict__ bout,
    float* __restrict__ out)
{
    const int blk = blockIdx.x;          // 0..511
    const int b   = blk >> 7;            // 128 blocks per batch
    const int h   = (blk >> 1) & 63;
    const int w0  = (blk & 1) * 32;
    const int tid = threadIdx.x;
    const int wv  = tid >> 6;            // o-tile
    const int l   = tid & 63;
    const int lg  = l >> 4, lr = l & 15;

    __shared__ __attribute__((aligned(16))) __hip_bfloat16 gvsh[2][32][72];
    __shared__ float gsh[32][NTAP];

    const int row0 = b * HW + h * 64 + w0;     // global pixel row of local w=0
    for (int i = tid; i < 32 * NTAP; i += 256) {
        const int w = i / NTAP, t = i - w * NTAP;
        gsh[w][t] = g[(size_t)(row0 + w) * NTAP + t];
    }

    f32x4 acc0 = {0.f, 0.f, 0.f, 0.f};
    f32x4 acc1 = {0.f, 0.f, 0.f, 0.f};
    const float4* vb = (const float4*)(v + ((size_t)b * HW) * COUT);
    const short* wb  = (const short*)W2b + (size_t)(wv * 16 + lr) * (NTAP * COUT);

    const int fw = tid >> 4;             // 0..15 (w for rep0; +16 for rep1)
    const int fc4 = tid & 15;            // float4 column

    __syncthreads();

    for (int t = 0; t < NTAP; ++t) {
        const int dh = t / 7 - 3, dw = t - (t / 7) * 7 - 3;
        const int jh = min(max(h + dh, 0), HH - 1);
        __hip_bfloat16* dstbuf = &gvsh[t & 1][0][0];
#pragma unroll
        for (int rep = 0; rep < 2; ++rep) {
            const int w  = fw + rep * 16;
            const int jw = min(max(w0 + w + dw, 0), WW - 1);
            const float4 vvv = vb[(size_t)((jh << 6) + jw) * 16 + fc4];
            const float gg = gsh[w][t];
            u16x4 pk;
            pk.x = __builtin_bit_cast(unsigned short, __float2bfloat16(vvv.x * gg));
            pk.y = __builtin_bit_cast(unsigned short, __float2bfloat16(vvv.y * gg));
            pk.z = __builtin_bit_cast(unsigned short, __float2bfloat16(vvv.z * gg));
            pk.w = __builtin_bit_cast(unsigned short, __float2bfloat16(vvv.w * gg));
            *(u16x4*)(dstbuf + w * 72 + fc4 * 4) = pk;
        }
        const bf16x8 b0 = *(const bf16x8*)(wb + t * 64 + lg * 8);
        const bf16x8 b1 = *(const bf16x8*)(wb + t * 64 + 32 + lg * 8);
        __syncthreads();
        const short* gsrc = (const short*)&gvsh[t & 1][0][0];
        const bf16x8 a00 = *(const bf16x8*)(gsrc + (size_t)lr * 72 + lg * 8);
        const bf16x8 a01 = *(const bf16x8*)(gsrc + (size_t)lr * 72 + 32 + lg * 8);
        const bf16x8 a10 = *(const bf16x8*)(gsrc + (size_t)(16 + lr) * 72 + lg * 8);
        const bf16x8 a11 = *(const bf16x8*)(gsrc + (size_t)(16 + lr) * 72 + 32 + lg * 8);
        acc0 = __builtin_amdgcn_mfma_f32_16x16x32_bf16(a00, b0, acc0, 0, 0, 0);
        acc0 = __builtin_amdgcn_mfma_f32_16x16x32_bf16(a01, b1, acc0, 0, 0, 0);
        acc1 = __builtin_amdgcn_mfma_f32_16x16x32_bf16(a10, b0, acc1, 0, 0, 0);
        acc1 = __builtin_amdgcn_mfma_f32_16x16x32_bf16(a11, b1, acc1, 0, 0, 0);
    }

    const int o  = wv * 16 + lr;
    const float bo = bout[o];
    float* obase = out + ((size_t)(b * COUT + o) * HW) + h * 64 + w0 + lg * 4;
    float4 r0, r1;
    r0.x = fmaxf(acc0.x + bo, 0.f); r0.y = fmaxf(acc0.y + bo, 0.f);
    r0.z = fmaxf(acc0.z + bo, 0.f); r0.w = fmaxf(acc0.w + bo, 0.f);
    r1.x = fmaxf(acc1.x + bo, 0.f); r1.y = fmaxf(acc1.y + bo, 0.f);
    r1.z = fmaxf(acc1.z + bo, 0.f); r1.w = fmaxf(acc1.w + bo, 0.f);
    *(float4*)obase        = r0;
    *(float4*)(obase + 16) = r1;
}

// ---------------------------------------------------------------------------
extern "C" void kernel_launch(void* const* d_in, const int* in_sizes, int n_in,
                              void* d_out, int out_size, void* d_ws, size_t ws_size,
                              hipStream_t stream)
{
    const float* x    = (const float*)d_in[0];
    const float* Wq   = (const float*)d_in[1];
    const float* bq   = (const float*)d_in[2];
    const float* Wk   = (const float*)d_in[3];
    const float* bk   = (const float*)d_in[4];
    const float* Wv   = (const float*)d_in[5];
    const float* bv   = (const float*)d_in[6];
    const float* Wout = (const float*)d_in[7];
    const float* bout = (const float*)d_in[8];
    float* out = (float*)d_out;

    // workspace layout (float units)
    float* ws      = (float*)d_ws;
    float* v       = ws;                                 // 1,048,576
    float* s_part  = v + (size_t)BATCH * HW * COUT;      // NSEG * B*HW
    float* g       = s_part + (size_t)NSEG * BATCH * HW; // 802,816
    float* bias192 = g + (size_t)BATCH * HW * NTAP;      // 192 (+pad)
    __hip_bfloat16* qh    = (__hip_bfloat16*)(bias192 + 256);
    __hip_bfloat16* kh    = qh + (size_t)BATCH * HW * COUT;
    __hip_bfloat16* W2b   = kh + (size_t)BATCH * HW * COUT;   // 200,704 bf16
    __hip_bfloat16* Wb192 = W2b + (size_t)COUT * NTAP * COUT; // 49,152 bf16

    prep_kernel<<<(192 * 256 + COUT * NTAP * COUT + 255) / 256, 256, 0, stream>>>(
        Wq, bq, Wk, bk, Wv, bv, Wout, Wb192, bias192, W2b);
    qkv_mfma<<<BATCH * (HW / 16), 256, 0, stream>>>(x, Wb192, bias192, v, qh, kh);
    qk_stats_mfma<<<BATCH * 16 * NSEG, 256, 0, stream>>>(qh, kh, s_part);
    gcalc_mfma<<<BATCH * HH * 7, 256, 0, stream>>>(qh, kh, s_part, g);
    out_mfma<<<512, 256, 0, stream>>>(g, v, W2b, bout, out);
}